// Round 1
// baseline (1094.108 us; speedup 1.0000x reference)
//
#include <hip/hip_runtime.h>
#include <hip/hip_bf16.h>
#include <math.h>
#include <stdint.h>

// ---------------------------------------------------------------------------
// GCN: 6 layers of  h' = act( segsum_dst( edge_val * (h @ W)[src] ) + b )
// dims: 512 -> 12 -> 10 -> 8 -> 6 -> 4 -> 7
// Strategy: build CSR-by-dst once per launch (atomic histogram + scan +
// scatter of packed (src,val)), then every aggregation is a gather with one
// non-atomic store per output element. Avoids ~150M float atomicAdds.
// ---------------------------------------------------------------------------

// ---------------- CSR build ----------------

__global__ void hist_kernel(const int* __restrict__ dst, int* __restrict__ counts, int E) {
    int i = blockIdx.x * blockDim.x + threadIdx.x;
    if (i < E) atomicAdd(&counts[dst[i]], 1);
}

__global__ void scan1_kernel(const int* __restrict__ counts, int* __restrict__ bsums, int N) {
    __shared__ int lds[256];
    int t = threadIdx.x;
    int i = blockIdx.x * 256 + t;
    lds[t] = (i < N) ? counts[i] : 0;
    __syncthreads();
    for (int off = 128; off > 0; off >>= 1) {
        if (t < off) lds[t] += lds[t + off];
        __syncthreads();
    }
    if (t == 0) bsums[blockIdx.x] = lds[0];
}

// single block of 512 threads: in-place exclusive scan of bsums (nb <= 512)
__global__ void scan2_kernel(int* __restrict__ bsums, int nb, int* __restrict__ row_ptr, int N) {
    __shared__ int lds[512];
    int t = threadIdx.x;
    int v = (t < nb) ? bsums[t] : 0;
    lds[t] = v;
    __syncthreads();
    for (int off = 1; off < 512; off <<= 1) {
        int x = (t >= off) ? lds[t - off] : 0;
        __syncthreads();
        lds[t] += x;
        __syncthreads();
    }
    if (t < nb) bsums[t] = lds[t] - v;      // exclusive block offset
    if (t == 0) row_ptr[N] = lds[511];      // total edge count
}

__global__ void scan3_kernel(const int* __restrict__ counts, const int* __restrict__ bsums,
                             int* __restrict__ row_ptr, int* __restrict__ cursor, int N) {
    __shared__ int lds[256];
    int t = threadIdx.x;
    int i = blockIdx.x * 256 + t;
    int v = (i < N) ? counts[i] : 0;
    lds[t] = v;
    __syncthreads();
    for (int off = 1; off < 256; off <<= 1) {
        int x = (t >= off) ? lds[t - off] : 0;
        __syncthreads();
        lds[t] += x;
        __syncthreads();
    }
    if (i < N) {
        int ex = bsums[blockIdx.x] + lds[t] - v;
        row_ptr[i] = ex;
        cursor[i]  = ex;
    }
}

__global__ void scatter_kernel(const int* __restrict__ src, const int* __restrict__ dst,
                               const float* __restrict__ val, int* __restrict__ cursor,
                               int2* __restrict__ edges, int E) {
    int i = blockIdx.x * blockDim.x + threadIdx.x;
    if (i < E) {
        int d   = dst[i];
        int pos = atomicAdd(&cursor[d], 1);
        edges[pos] = make_int2(src[i], __float_as_int(val[i]));
    }
}

// ---------------- layer 1 dense: s = x @ W1  (N x 512) @ (512 x 12) ----------------
// 256 rows/block, thread-per-row, k tiled by 32 through LDS (stride 33 pad).
// W accessed with wave-uniform index -> scalar loads.

__global__ __launch_bounds__(256) void dense1_kernel(const float* __restrict__ x,
                                                     const float* __restrict__ W,
                                                     float* __restrict__ out, int N) {
    __shared__ float xs[256 * 33];
    const int t    = threadIdx.x;
    const int row0 = blockIdx.x * 256;
    const int r    = row0 + t;

    float acc[12];
#pragma unroll
    for (int j = 0; j < 12; j++) acc[j] = 0.f;

    for (int tile = 0; tile < 16; ++tile) {
        // cooperative coalesced load of 256 rows x 32 cols (float4 per thread x8)
#pragma unroll
        for (int i = 0; i < 8; i++) {
            int idx4 = t + 256 * i;       // float4 index within tile
            int flat = idx4 * 4;
            int rl   = flat >> 5;         // local row
            int c    = flat & 31;         // col within tile
            int rg   = row0 + rl;
            if (rg >= N) rg = N - 1;      // clamp for OOB rows (values unused)
            const float4 v = *(const float4*)(x + (size_t)rg * 512 + tile * 32 + c);
            float* p = &xs[rl * 33 + c];
            p[0] = v.x; p[1] = v.y; p[2] = v.z; p[3] = v.w;
        }
        __syncthreads();
#pragma unroll 8
        for (int kk = 0; kk < 32; ++kk) {
            float xv = xs[t * 33 + kk];   // lane stride 33 -> conflict-free
            int k = tile * 32 + kk;       // wave-uniform
#pragma unroll
            for (int j = 0; j < 12; j++) acc[j] += xv * W[k * 12 + j];  // s_load W
        }
        __syncthreads();
    }
    if (r < N) {
#pragma unroll
        for (int j = 0; j < 12; j++) out[(size_t)r * 12 + j] = acc[j];
    }
}

// ---------------- small dense layers: s = act(in + b_prev) @ W ----------------
// ACT: 0 = none, 1 = relu, 2 = tanhshrink

template <int DIN, int DOUT, int ACT>
__global__ void dense_small_kernel(const float* __restrict__ in, const float* __restrict__ bias,
                                   const float* __restrict__ W, float* __restrict__ out, int N) {
    int r = blockIdx.x * blockDim.x + threadIdx.x;
    if (r >= N) return;
    float v[DIN];
#pragma unroll
    for (int k = 0; k < DIN; k++) {
        float h = in[(size_t)r * DIN + k] + bias[k];
        if (ACT == 1) h = fmaxf(h, 0.f);
        else if (ACT == 2) h = h - tanhf(h);
        v[k] = h;
    }
#pragma unroll
    for (int j = 0; j < DOUT; j++) {
        float s = 0.f;
#pragma unroll
        for (int k = 0; k < DIN; k++) s += v[k] * W[k * DOUT + j];
        out[(size_t)r * DOUT + j] = s;
    }
}

// ---------------- CSR gather: agg[n,j] = sum_e val_e * s[src_e, j] ----------------
// thread = (node, j); D threads of a node read the same edge record (broadcast).

template <int D, bool FINAL>
__global__ void gather_kernel(const int2* __restrict__ edges, const int* __restrict__ row_ptr,
                              const float* __restrict__ s, const float* __restrict__ bias,
                              float* __restrict__ out, int N) {
    int tid  = blockIdx.x * blockDim.x + threadIdx.x;
    int node = tid / D;
    int j    = tid % D;
    if (node >= N) return;
    int e0 = row_ptr[node];
    int e1 = row_ptr[node + 1];
    float acc = 0.f;
    for (int e = e0; e < e1; ++e) {
        int2 ev = edges[e];
        acc += __int_as_float(ev.y) * s[(size_t)ev.x * D + j];
    }
    if (FINAL) acc += bias[j];
    out[(size_t)node * D + j] = acc;
}

// ---------------- launcher ----------------

static inline size_t align256(size_t x) { return (x + 255) & ~(size_t)255; }

extern "C" void kernel_launch(void* const* d_in, const int* in_sizes, int n_in,
                              void* d_out, int out_size, void* d_ws, size_t ws_size,
                              hipStream_t stream) {
    const float* x        = (const float*)d_in[0];
    const float* edge_val = (const float*)d_in[1];
    const int*   edge_src = (const int*)d_in[2];
    const int*   edge_dst = (const int*)d_in[3];
    const float* W1 = (const float*)d_in[4];   const float* b1 = (const float*)d_in[5];
    const float* W2 = (const float*)d_in[6];   const float* b2 = (const float*)d_in[7];
    const float* W3 = (const float*)d_in[8];   const float* b3 = (const float*)d_in[9];
    const float* W4 = (const float*)d_in[10];  const float* b4 = (const float*)d_in[11];
    const float* W5 = (const float*)d_in[12];  const float* b5 = (const float*)d_in[13];
    const float* W6 = (const float*)d_in[14];  const float* b6 = (const float*)d_in[15];

    const int N = in_sizes[0] / 512;   // 100000
    const int E = in_sizes[1];         // 3200000
    float* out = (float*)d_out;

    // workspace carve-up (256B aligned regions)
    char* w = (char*)d_ws;
    float* A       = (float*)w;  w += align256((size_t)N * 12 * sizeof(float));
    float* B       = (float*)w;  w += align256((size_t)N * 12 * sizeof(float));
    int*   counts  = (int*)w;    w += align256((size_t)N * sizeof(int));
    int*   row_ptr = (int*)w;    w += align256((size_t)(N + 1) * sizeof(int));
    int*   cursor  = (int*)w;    w += align256((size_t)N * sizeof(int));
    int*   bsums   = (int*)w;    w += align256(512 * sizeof(int));
    int2*  edges   = (int2*)w;   w += align256((size_t)E * sizeof(int2));

    const int nb  = (N + 255) / 256;   // 391 (<=512 required by scan2)
    const int ebl = (E + 255) / 256;

    // ---- CSR build (once per launch, reused by all 6 layers) ----
    hipMemsetAsync(counts, 0, (size_t)N * sizeof(int), stream);
    hist_kernel<<<ebl, 256, 0, stream>>>(edge_dst, counts, E);
    scan1_kernel<<<nb, 256, 0, stream>>>(counts, bsums, N);
    scan2_kernel<<<1, 512, 0, stream>>>(bsums, nb, row_ptr, N);
    scan3_kernel<<<nb, 256, 0, stream>>>(counts, bsums, row_ptr, cursor, N);
    scatter_kernel<<<ebl, 256, 0, stream>>>(edge_src, edge_dst, edge_val, cursor, edges, E);

    // ---- layer 1: s1 = x @ W1 ; agg -> B (h1 = B + b1 deferred) ----
    dense1_kernel<<<nb, 256, 0, stream>>>(x, W1, A, N);
    gather_kernel<12, false><<<(int)(((size_t)N * 12 + 255) / 256), 256, 0, stream>>>(edges, row_ptr, A, b1, B, N);

    // ---- layer 2: s2 = (B + b1) @ W2 ; agg -> B ----
    dense_small_kernel<12, 10, 0><<<nb, 256, 0, stream>>>(B, b1, W2, A, N);
    gather_kernel<10, false><<<(int)(((size_t)N * 10 + 255) / 256), 256, 0, stream>>>(edges, row_ptr, A, b2, B, N);

    // ---- layer 3: s3 = relu(B + b2) @ W3 ----
    dense_small_kernel<10, 8, 1><<<nb, 256, 0, stream>>>(B, b2, W3, A, N);
    gather_kernel<8, false><<<(int)(((size_t)N * 8 + 255) / 256), 256, 0, stream>>>(edges, row_ptr, A, b3, B, N);

    // ---- layer 4: s4 = tanhshrink(B + b3) @ W4 ----
    dense_small_kernel<8, 6, 2><<<nb, 256, 0, stream>>>(B, b3, W4, A, N);
    gather_kernel<6, false><<<(int)(((size_t)N * 6 + 255) / 256), 256, 0, stream>>>(edges, row_ptr, A, b4, B, N);

    // ---- layer 5: s5 = tanhshrink(B + b4) @ W5 ----
    dense_small_kernel<6, 4, 2><<<nb, 256, 0, stream>>>(B, b4, W5, A, N);
    gather_kernel<4, false><<<(int)(((size_t)N * 4 + 255) / 256), 256, 0, stream>>>(edges, row_ptr, A, b5, B, N);

    // ---- layer 6: s6 = (B + b5) @ W6 ; agg + b6 -> out ----
    dense_small_kernel<4, 7, 0><<<nb, 256, 0, stream>>>(B, b5, W6, A, N);
    gather_kernel<7, true><<<(int)(((size_t)N * 7 + 255) / 256), 256, 0, stream>>>(edges, row_ptr, A, b6, out, N);
}